// Round 1
// baseline (77.458 us; speedup 1.0000x reference)
//
#include <hip/hip_runtime.h>
#include <hip/hip_bf16.h>
#include <stdint.h>

typedef __attribute__((ext_vector_type(4))) float f32x4;
typedef __attribute__((ext_vector_type(8))) short bf16x8;

#define NCH  128
#define NREL 8

__device__ __forceinline__ unsigned short f2bf(float f) {
    unsigned u = __builtin_bit_cast(unsigned, f);
    u += 0x7fffu + ((u >> 16) & 1u);          // RNE to bf16
    return (unsigned short)(u >> 16);
}

// ---------------------------------------------------------------------------
// k_prep: W fp32 [8][128][128] -> bf16 Wb laid out for B-fragment loads:
//   Wb[((kt*128 + col) << 5) + kk] = bf16(W[k=kt*32+kk][col]),  k = r*128+c
// also zeroes the compaction counter and detects used_mask element width.
// ---------------------------------------------------------------------------
__global__ void k_prep(const float* __restrict__ W, unsigned short* __restrict__ Wb,
                       int* __restrict__ cn, const unsigned char* __restrict__ um_raw) {
    int o = blockIdx.x * 256 + threadIdx.x;
    if (o < NREL * NCH * NCH) {
        int kk = o & 31;
        int h  = (o >> 5) & (NCH - 1);
        int kt = o >> 12;
        int k  = kt * 32 + kk;
        Wb[o] = f2bf(W[k * NCH + h]);
    }
    if (o == 0) {
        cn[0] = 0;
        // mask width detect: bool kept as 1B => bytes at p%4!=0 are data (~95% ones)
        // int32 => only p%4==0 may be nonzero; int64 => only p%8==0.
        unsigned a = 0, b = 0;
        for (int p = 0; p < 1024; ++p) {
            unsigned v = um_raw[p];
            if ((p & 3) != 0) a |= v;
            if ((p & 7) == 4) b |= v;
        }
        cn[1] = a ? 1 : (b ? 4 : 8);          // element stride in bytes
    }
}

__device__ __forceinline__ bool mask_used(const unsigned char* um, int stride, int s) {
    if (stride == 1) return um[s] != 0;
    if (stride == 4) return ((const int*)um)[s] != 0;
    return ((const long long*)um)[s] != 0;
}

// ---------------------------------------------------------------------------
// k_hist: copy history rows to out for cached nodes; compact non-cached ids.
// ---------------------------------------------------------------------------
__global__ __launch_bounds__(256)
void k_hist(const float* __restrict__ hb, const int* __restrict__ hm,
            const int* __restrict__ hs, float* __restrict__ out,
            int* __restrict__ cn, int* __restrict__ glist, int num_node) {
    __shared__ int ncList[256];
    __shared__ int cList[256];
    __shared__ int nNC, nC, gbase;
    const int t = threadIdx.x;
    if (t == 0) { nNC = 0; nC = 0; }
    __syncthreads();
    const int n = blockIdx.x * 256 + t;
    if (n < num_node) {
        const bool cached = (hs[0] > 0) && (hm[n] != -1);
        if (cached) { int p = atomicAdd(&nC, 1);  cList[p]  = n; }
        else        { int p = atomicAdd(&nNC, 1); ncList[p] = n; }
    }
    __syncthreads();
    // half-wave (32 lanes) per cached row: 32 x float4 = 512B
    const int hw = t >> 5, l = t & 31;
    for (int i = hw; i < nC; i += 8) {
        const int node = cList[i];
        f32x4 v = *(const f32x4*)(hb + (long)node * NCH + l * 4);
        *(f32x4*)(out + (long)node * NCH + l * 4) = v;
    }
    if (t == 0) gbase = atomicAdd(&cn[0], nNC);
    __syncthreads();
    if (t < nNC) glist[gbase + t] = ncList[t];
}

// ---------------------------------------------------------------------------
// k_main: 16 non-cached nodes per 256-thread block.
//   phase 1: half-wave per node aggregates s[8][128] fp32 in regs, -> bf16 LDS
//   phase 2: out[16x128] = A[16x1024] * Wb[1024x128] via mfma 16x16x32 bf16
// ---------------------------------------------------------------------------
__global__ __launch_bounds__(256, 4)
void k_main(const float* __restrict__ x, const unsigned short* __restrict__ Wb,
            const int* __restrict__ ptr, const int* __restrict__ idx,
            const int* __restrict__ et, const unsigned char* __restrict__ um,
            const int* __restrict__ cn, const int* __restrict__ glist,
            float* __restrict__ out) {
    __shared__ __align__(16) char As[16 * NREL * NCH * 2];   // 32 KB, XOR-swizzled
    __shared__ int   nid[16];
    __shared__ float invdeg[16];

    const int cnt  = cn[0];
    const int base = blockIdx.x * 16;
    if (base >= cnt) return;
    const int mstride = cn[1];
    const int t = threadIdx.x;
    if (t < 16) {
        const int e = base + t;
        nid[t]    = (e < cnt) ? glist[e] : -1;
        invdeg[t] = 0.0f;
    }
    __syncthreads();

    const int hw = t >> 5;          // half-wave id 0..7
    const int l  = t & 31;          // lane in half-wave; owns channels 4l..4l+3
    const int lbase = t & 32;       // wave-lane base of this half-wave

    for (int rep = 0; rep < 2; ++rep) {
        const int nd = hw + rep * 8;
        const int n  = nid[nd];
        float acc[NREL][4];
        #pragma unroll
        for (int r = 0; r < NREL; ++r) {
            #pragma unroll
            for (int j = 0; j < 4; ++j) acc[r][j] = 0.0f;
        }
        if (n >= 0) {
            const int p0 = ptr[n], p1 = ptr[n + 1];
            const int deg = p1 - p0;
            if (l == 0) invdeg[nd] = (deg > 0) ? 1.0f / (float)deg : 0.0f;
            // lane-parallel metadata gather for up to 16 edges
            int myS = 0, myR = NREL;
            if (l < 16 && (p0 + l) < p1) {
                const int e = p0 + l;
                myS = idx[e];
                const int tt = et[e];
                myR = (mask_used(um, mstride, myS) && tt >= 0 && tt < NREL) ? tt : NREL;
            }
            const int dcap = deg < 16 ? deg : 16;
            for (int e = 0; e < dcap; ++e) {
                const int r = __shfl(myR, lbase + e, 64);
                const int s = __shfl(myS, lbase + e, 64);
                if (r < NREL) {
                    const f32x4 xv = *(const f32x4*)(x + (long)s * NCH + l * 4);
                    #pragma unroll
                    for (int rr = 0; rr < NREL; ++rr) {
                        const float sel = (r == rr) ? 1.0f : 0.0f;
                        acc[rr][0] += sel * xv.x;
                        acc[rr][1] += sel * xv.y;
                        acc[rr][2] += sel * xv.z;
                        acc[rr][3] += sel * xv.w;
                    }
                }
            }
            for (int e = p0 + 16; e < p1; ++e) {   // general fallback (deg > 16)
                const int s = idx[e];
                const int tt = et[e];
                if (mask_used(um, mstride, s) && tt >= 0 && tt < NREL) {
                    const f32x4 xv = *(const f32x4*)(x + (long)s * NCH + l * 4);
                    #pragma unroll
                    for (int rr = 0; rr < NREL; ++rr) {
                        const float sel = (tt == rr) ? 1.0f : 0.0f;
                        acc[rr][0] += sel * xv.x;
                        acc[rr][1] += sel * xv.y;
                        acc[rr][2] += sel * xv.z;
                        acc[rr][3] += sel * xv.w;
                    }
                }
            }
        }
        // bf16 pack -> swizzled LDS A[nd][k], k = rr*128 + 4l + j
        #pragma unroll
        for (int rr = 0; rr < NREL; ++rr) {
            ushort4 pk;
            pk.x = f2bf(acc[rr][0]); pk.y = f2bf(acc[rr][1]);
            pk.z = f2bf(acc[rr][2]); pk.w = f2bf(acc[rr][3]);
            const int eb   = (rr * NCH + l * 4) * 2;
            const int addr = (nd * 2048 + eb) ^ ((nd & 7) << 4);
            *(ushort4*)(As + addr) = pk;
        }
    }
    __syncthreads();

    // phase 2: MFMA. wave wv covers output cols [wv*32, wv*32+32)
    const int wv   = t >> 6;
    const int lane = t & 63;
    const int row  = lane & 15;
    const int koff = (lane >> 4) * 8;
    const int n0   = wv * 32;
    const int col0 = n0 + row;
    f32x4 c0 = {0.f, 0.f, 0.f, 0.f}, c1 = {0.f, 0.f, 0.f, 0.f};
    #pragma unroll 8
    for (int kt = 0; kt < 32; ++kt) {
        const int aaddr = (row * 2048 + (kt * 32 + koff) * 2) ^ ((row & 7) << 4);
        const bf16x8 a  = *(const bf16x8*)(As + aaddr);
        const bf16x8 b0 = *(const bf16x8*)(Wb + ((kt * NCH + col0) << 5) + koff);
        const bf16x8 b1 = *(const bf16x8*)(Wb + ((kt * NCH + col0 + 16) << 5) + koff);
        c0 = __builtin_amdgcn_mfma_f32_16x16x32_bf16(a, b0, c0, 0, 0, 0);
        c1 = __builtin_amdgcn_mfma_f32_16x16x32_bf16(a, b1, c1, 0, 0, 0);
    }
    const int r4 = (lane >> 4) * 4;
    #pragma unroll
    for (int j = 0; j < 4; ++j) {
        const int rr = r4 + j;
        const int n  = nid[rr];
        if (n >= 0) {
            const float sc = invdeg[rr];
            out[(long)n * NCH + col0]      = c0[j] * sc;
            out[(long)n * NCH + col0 + 16] = c1[j] * sc;
        }
    }
}

extern "C" void kernel_launch(void* const* d_in, const int* in_sizes, int n_in,
                              void* d_out, int out_size, void* d_ws, size_t ws_size,
                              hipStream_t stream) {
    const float*         x   = (const float*)d_in[0];
    const float*         W   = (const float*)d_in[1];
    const float*         hb  = (const float*)d_in[2];
    const int*           ptr = (const int*)d_in[3];
    const int*           idx = (const int*)d_in[4];
    const int*           et  = (const int*)d_in[5];
    const unsigned char* um  = (const unsigned char*)d_in[6];
    const int*           hm  = (const int*)d_in[7];
    const int*           hs  = (const int*)d_in[8];
    float* out = (float*)d_out;

    const int num_node = in_sizes[7];           // history_map length

    // ws layout: [0..7] int cn (count, mask stride), glist, Wb
    int* cn    = (int*)d_ws;
    int* glist = (int*)((char*)d_ws + 256);
    size_t wb_off = 256 + (((size_t)num_node * 4 + 255) / 256) * 256;
    unsigned short* Wb = (unsigned short*)((char*)d_ws + wb_off);

    k_prep<<<(NREL * NCH * NCH + 255) / 256, 256, 0, stream>>>(W, Wb, cn, um);
    k_hist<<<(num_node + 255) / 256, 256, 0, stream>>>(hb, hm, hs, out, cn, glist, num_node);
    k_main<<<(num_node + 15) / 16, 256, 0, stream>>>(x, Wb, ptr, idx, et, um, cn, glist, out);
}

// Round 2
// 67.950 us; speedup vs baseline: 1.1399x; 1.1399x over previous
//
#include <hip/hip_runtime.h>
#include <hip/hip_bf16.h>
#include <stdint.h>

typedef __attribute__((ext_vector_type(4))) float f32x4;
typedef __attribute__((ext_vector_type(8))) short bf16x8;

#define NCH  128
#define NREL 8

__device__ __forceinline__ unsigned short f2bf(float f) {
    unsigned u = __builtin_bit_cast(unsigned, f);
    u += 0x7fffu + ((u >> 16) & 1u);          // RNE to bf16
    return (unsigned short)(u >> 16);
}

// ---------------------------------------------------------------------------
// k_prep: W fp32 [8][128][128] -> bf16 Wb laid out for B-fragment loads:
//   Wb[((kt*128 + col) << 5) + kk] = bf16(W[k=kt*32+kk][col]),  k = r*128+c
// block 0 also zeroes the compaction counter and detects used_mask width
// (parallel across 256 threads -- the R1 version did this serially on ONE
// lane: ~1024 global byte loads from a single thread).
// ---------------------------------------------------------------------------
__global__ __launch_bounds__(256)
void k_prep(const float* __restrict__ W, unsigned short* __restrict__ Wb,
            int* __restrict__ cn, const unsigned char* __restrict__ um_raw) {
    int o = blockIdx.x * 256 + threadIdx.x;
    if (o < NREL * NCH * NCH) {
        int kk = o & 31;
        int h  = (o >> 5) & (NCH - 1);
        int kt = o >> 12;
        int k  = kt * 32 + kk;
        Wb[o] = f2bf(W[k * NCH + h]);
    }
    if (blockIdx.x == 0) {
        __shared__ unsigned sA, sB;
        const int t = threadIdx.x;
        if (t == 0) { sA = 0; sB = 0; }
        __syncthreads();
        unsigned a = 0, b = 0;
        #pragma unroll 4
        for (int p = t; p < 1024; p += 256) {
            unsigned v = um_raw[p];
            if ((p & 3) != 0) a |= v;
            if ((p & 7) == 4) b |= v;
        }
        if (a) atomicOr(&sA, 1u);
        if (b) atomicOr(&sB, 1u);
        __syncthreads();
        if (t == 0) {
            cn[0] = 0;
            cn[1] = sA ? 1 : (sB ? 4 : 8);    // mask element stride in bytes
        }
    }
}

__device__ __forceinline__ bool mask_used(const unsigned char* um, int stride, int s) {
    if (stride == 1) return um[s] != 0;
    if (stride == 4) return ((const int*)um)[s] != 0;
    return ((const long long*)um)[s] != 0;
}

// ---------------------------------------------------------------------------
// k_hist: 32 nodes per 256-thread block (2048 blocks -> full occupancy).
// Copy history rows to out for cached nodes (4-deep load/store pipeline);
// compact non-cached ids to glist.
// ---------------------------------------------------------------------------
__global__ __launch_bounds__(256)
void k_hist(const float* __restrict__ hb, const int* __restrict__ hm,
            const int* __restrict__ hs, float* __restrict__ out,
            int* __restrict__ cn, int* __restrict__ glist, int num_node) {
    __shared__ int ncList[32];
    __shared__ int cList[32];
    __shared__ int nNC, nC, gbase;
    const int t = threadIdx.x;
    if (t == 0) { nNC = 0; nC = 0; }
    __syncthreads();
    const int n = blockIdx.x * 32 + t;
    if (t < 32 && n < num_node) {
        const bool cached = (hs[0] > 0) && (hm[n] != -1);
        if (cached) { int p = atomicAdd(&nC, 1);  cList[p]  = n; }
        else        { int p = atomicAdd(&nNC, 1); ncList[p] = n; }
    }
    __syncthreads();
    // half-wave (32 lanes) per row; candidate rows hw, hw+8, hw+16, hw+24
    const int hw = t >> 5, l = t & 31;
    int   node[4];
    f32x4 v[4];
    #pragma unroll 4
    for (int j = 0; j < 4; ++j) {
        const int i = hw + j * 8;
        node[j] = (i < nC) ? cList[i] : -1;
        if (node[j] >= 0)
            v[j] = *(const f32x4*)(hb + (long)node[j] * NCH + l * 4);
    }
    #pragma unroll 4
    for (int j = 0; j < 4; ++j) {
        if (node[j] >= 0)
            *(f32x4*)(out + (long)node[j] * NCH + l * 4) = v[j];
    }
    if (t == 0) gbase = atomicAdd(&cn[0], nNC);
    __syncthreads();
    if (t < nNC) glist[gbase + t] = ncList[t];
}

// ---------------------------------------------------------------------------
// k_main: 16 non-cached nodes per 256-thread block.
//   phase 1: half-wave per node aggregates s[8][128] fp32 in regs
//            (gathers issued unconditionally, 8 outstanding per half-wave),
//            -> bf16 swizzled LDS A-tile [16][1024]
//   phase 2: out[16x128] = A[16x1024] * Wb[1024x128] via mfma 16x16x32 bf16
// ---------------------------------------------------------------------------
__global__ __launch_bounds__(256, 4)
void k_main(const float* __restrict__ x, const unsigned short* __restrict__ Wb,
            const int* __restrict__ ptr, const int* __restrict__ idx,
            const int* __restrict__ et, const unsigned char* __restrict__ um,
            const int* __restrict__ cn, const int* __restrict__ glist,
            float* __restrict__ out) {
    __shared__ __align__(16) char As[16 * NREL * NCH * 2];   // 32 KB, XOR-swizzled
    __shared__ int   nid[16];
    __shared__ float invdeg[16];

    const int cnt  = cn[0];
    const int base = blockIdx.x * 16;
    if (base >= cnt) return;
    const int mstride = cn[1];
    const int t = threadIdx.x;
    if (t < 16) {
        const int e = base + t;
        nid[t]    = (e < cnt) ? glist[e] : -1;
        invdeg[t] = 0.0f;
    }
    __syncthreads();

    const int hw = t >> 5;          // half-wave id 0..7
    const int l  = t & 31;          // lane in half-wave; owns channels 4l..4l+3
    const int lbase = t & 32;       // wave-lane base of this half-wave

    for (int rep = 0; rep < 2; ++rep) {
        const int nd = hw + rep * 8;
        const int n  = nid[nd];
        float acc[NREL][4];
        #pragma unroll
        for (int r = 0; r < NREL; ++r) {
            #pragma unroll
            for (int j = 0; j < 4; ++j) acc[r][j] = 0.0f;
        }
        if (n >= 0) {
            const int p0 = ptr[n], p1 = ptr[n + 1];
            const int deg = p1 - p0;
            if (l == 0) invdeg[nd] = (deg > 0) ? 1.0f / (float)deg : 0.0f;
            // lane-parallel metadata gather for up to 16 edges
            int myS = 0, myR = NREL;   // defaults: row 0, dead relation
            if (l < 16 && (p0 + l) < p1) {
                const int e = p0 + l;
                myS = idx[e];
                const int tt = et[e];
                myR = (mask_used(um, mstride, myS) && tt >= 0 && tt < NREL) ? tt : NREL;
            }
            // two chunks of 8 edges; loads unconditional (idx always valid),
            // dead edges contribute via sel = 0.
            #pragma unroll 2
            for (int ch = 0; ch < 2; ++ch) {
                int   rr8[8], ss8[8];
                f32x4 xv[8];
                #pragma unroll 8
                for (int e = 0; e < 8; ++e) {
                    rr8[e] = __shfl(myR, lbase + ch * 8 + e, 64);
                    ss8[e] = __shfl(myS, lbase + ch * 8 + e, 64);
                    xv[e]  = *(const f32x4*)(x + (long)ss8[e] * NCH + l * 4);
                }
                #pragma unroll 8
                for (int e = 0; e < 8; ++e) {
                    const int r = rr8[e];
                    #pragma unroll
                    for (int q = 0; q < NREL; ++q) {
                        const float sel = (r == q) ? 1.0f : 0.0f;
                        acc[q][0] += sel * xv[e].x;
                        acc[q][1] += sel * xv[e].y;
                        acc[q][2] += sel * xv[e].z;
                        acc[q][3] += sel * xv[e].w;
                    }
                }
            }
            for (int e = p0 + 16; e < p1; ++e) {   // general fallback (deg > 16)
                const int s = idx[e];
                const int tt = et[e];
                if (mask_used(um, mstride, s) && tt >= 0 && tt < NREL) {
                    const f32x4 xv = *(const f32x4*)(x + (long)s * NCH + l * 4);
                    #pragma unroll
                    for (int q = 0; q < NREL; ++q) {
                        const float sel = (tt == q) ? 1.0f : 0.0f;
                        acc[q][0] += sel * xv.x;
                        acc[q][1] += sel * xv.y;
                        acc[q][2] += sel * xv.z;
                        acc[q][3] += sel * xv.w;
                    }
                }
            }
        }
        // bf16 pack -> swizzled LDS A[nd][k], k = q*128 + 4l + j
        #pragma unroll
        for (int q = 0; q < NREL; ++q) {
            ushort4 pk;
            pk.x = f2bf(acc[q][0]); pk.y = f2bf(acc[q][1]);
            pk.z = f2bf(acc[q][2]); pk.w = f2bf(acc[q][3]);
            const int eb   = (q * NCH + l * 4) * 2;
            const int addr = (nd * 2048 + eb) ^ ((nd & 7) << 4);
            *(ushort4*)(As + addr) = pk;
        }
    }
    __syncthreads();

    // phase 2: MFMA. wave wv covers output cols [wv*32, wv*32+32)
    const int wv   = t >> 6;
    const int lane = t & 63;
    const int row  = lane & 15;
    const int koff = (lane >> 4) * 8;
    const int col0 = wv * 32 + row;
    f32x4 c0 = {0.f, 0.f, 0.f, 0.f}, c1 = {0.f, 0.f, 0.f, 0.f};
    #pragma unroll 8
    for (int kt = 0; kt < 32; ++kt) {
        const int aaddr = (row * 2048 + (kt * 32 + koff) * 2) ^ ((row & 7) << 4);
        const bf16x8 a  = *(const bf16x8*)(As + aaddr);
        const bf16x8 b0 = *(const bf16x8*)(Wb + ((kt * NCH + col0) << 5) + koff);
        const bf16x8 b1 = *(const bf16x8*)(Wb + ((kt * NCH + col0 + 16) << 5) + koff);
        c0 = __builtin_amdgcn_mfma_f32_16x16x32_bf16(a, b0, c0, 0, 0, 0);
        c1 = __builtin_amdgcn_mfma_f32_16x16x32_bf16(a, b1, c1, 0, 0, 0);
    }
    const int r4 = (lane >> 4) * 4;
    #pragma unroll
    for (int j = 0; j < 4; ++j) {
        const int rr = r4 + j;
        const int n  = nid[rr];
        if (n >= 0) {
            const float sc = invdeg[rr];
            out[(long)n * NCH + col0]      = c0[j] * sc;
            out[(long)n * NCH + col0 + 16] = c1[j] * sc;
        }
    }
}

extern "C" void kernel_launch(void* const* d_in, const int* in_sizes, int n_in,
                              void* d_out, int out_size, void* d_ws, size_t ws_size,
                              hipStream_t stream) {
    const float*         x   = (const float*)d_in[0];
    const float*         W   = (const float*)d_in[1];
    const float*         hb  = (const float*)d_in[2];
    const int*           ptr = (const int*)d_in[3];
    const int*           idx = (const int*)d_in[4];
    const int*           et  = (const int*)d_in[5];
    const unsigned char* um  = (const unsigned char*)d_in[6];
    const int*           hm  = (const int*)d_in[7];
    const int*           hs  = (const int*)d_in[8];
    float* out = (float*)d_out;

    const int num_node = in_sizes[7];           // history_map length

    // ws layout: [0..7] int cn (count, mask stride), glist, Wb
    int* cn    = (int*)d_ws;
    int* glist = (int*)((char*)d_ws + 256);
    size_t wb_off = 256 + (((size_t)num_node * 4 + 255) / 256) * 256;
    unsigned short* Wb = (unsigned short*)((char*)d_ws + wb_off);

    k_prep<<<(NREL * NCH * NCH + 255) / 256, 256, 0, stream>>>(W, Wb, cn, um);
    k_hist<<<(num_node + 31) / 32, 256, 0, stream>>>(hb, hm, hs, out, cn, glist, num_node);
    k_main<<<(num_node + 15) / 16, 256, 0, stream>>>(x, Wb, ptr, idx, et, um, cn, glist, out);
}